// Round 1
// baseline (226.160 us; speedup 1.0000x reference)
//
#include <hip/hip_runtime.h>

// Depthwise Conv1d: B=32, C=128, L=8192, K=3, pad=1, fp32.
// out[b,c,l] = w[c,0]*x[b,c,l-1] + w[c,1]*x[b,c,l] + w[c,2]*x[b,c,l+1] + bias[c]
// (zero padding at l=-1 and l=L). Memory-bound: ~268 MB total traffic.

constexpr int C = 128;
constexpr int L = 8192;
constexpr int L4 = L / 4;        // 2048 float4 per row
constexpr int B = 32;
constexpr int TOTAL4 = B * C * L4; // 8,388,608

__global__ __launch_bounds__(256) void dwconv1d_kernel(
    const float4* __restrict__ x4,
    const float* __restrict__ x,      // same buffer, scalar view for halo loads
    const float* __restrict__ w,      // [C,3]
    const float* __restrict__ bias,   // [C]
    float4* __restrict__ out4)
{
    int idx = blockIdx.x * blockDim.x + threadIdx.x;
    if (idx >= TOTAL4) return;

    int i4  = idx & (L4 - 1);        // position within row (in float4 units)
    int row = idx >> 11;             // b*C + c
    int c   = row & (C - 1);

    float w0 = w[c * 3 + 0];
    float w1 = w[c * 3 + 1];
    float w2 = w[c * 3 + 2];
    float bc = bias[c];

    float4 v = x4[idx];
    long base = (long)idx * 4;

    // halo elements; zero at row boundaries (padding=1)
    float left  = (i4 == 0)      ? 0.0f : x[base - 1];
    float right = (i4 == L4 - 1) ? 0.0f : x[base + 4];

    float4 o;
    o.x = fmaf(w0, left, fmaf(w1, v.x, fmaf(w2, v.y, bc)));
    o.y = fmaf(w0, v.x,  fmaf(w1, v.y, fmaf(w2, v.z, bc)));
    o.z = fmaf(w0, v.y,  fmaf(w1, v.z, fmaf(w2, v.w, bc)));
    o.w = fmaf(w0, v.z,  fmaf(w1, v.w, fmaf(w2, right, bc)));

    out4[idx] = o;
}

extern "C" void kernel_launch(void* const* d_in, const int* in_sizes, int n_in,
                              void* d_out, int out_size, void* d_ws, size_t ws_size,
                              hipStream_t stream)
{
    const float* x    = (const float*)d_in[0];  // [B,C,L]
    const float* w    = (const float*)d_in[1];  // [C,3]
    const float* bias = (const float*)d_in[2];  // [C]
    float* out        = (float*)d_out;

    const int block = 256;
    const int grid  = (TOTAL4 + block - 1) / block; // 32768

    dwconv1d_kernel<<<grid, block, 0, stream>>>(
        (const float4*)x, x, w, bias, (float4*)out);
}

// Round 2
// 224.880 us; speedup vs baseline: 1.0057x; 1.0057x over previous
//
#include <hip/hip_runtime.h>

// Depthwise Conv1d: B=32, C=128, L=8192, K=3, pad=1, fp32.
// out[b,c,l] = w[c,0]*x[b,c,l-1] + w[c,1]*x[b,c,l] + w[c,2]*x[b,c,l+1] + bias[c]
// Memory-bound: ideal traffic 128 MiB read + 128 MiB write → ~43 µs @ 6.3 TB/s.
//
// Layout exploit: L4 = 2048 float4 per row, so a 64-lane wave never spans a
// row boundary (2048 % 64 == 0) → channel is wave-uniform (weights via s_load),
// and halo elements come from neighbor lanes via shuffle (only lanes 0/63 do
// an extra exec-masked scalar load, 2 loads/wave instead of 128).

constexpr int C  = 128;
constexpr int L  = 8192;
constexpr int L4 = L / 4;          // 2048 float4 per row
constexpr int B  = 32;
constexpr int TOTAL4 = B * C * L4; // 8,388,608 (exact multiple of 256)

__global__ __launch_bounds__(256) void dwconv1d_kernel(
    const float4* __restrict__ x4,
    const float* __restrict__ x,      // scalar view of same buffer (edge halos)
    const float* __restrict__ w,      // [C,3]
    const float* __restrict__ bias,   // [C]
    float4* __restrict__ out4)
{
    int idx  = blockIdx.x * blockDim.x + threadIdx.x;
    int lane = threadIdx.x & 63;
    int i4   = idx & (L4 - 1);       // position within row (float4 units)

    // Channel is identical across the wave -> force scalar (s_load) path.
    int c = __builtin_amdgcn_readfirstlane((idx >> 11) & (C - 1));
    float w0 = w[c * 3 + 0];
    float w1 = w[c * 3 + 1];
    float w2 = w[c * 3 + 2];
    float bc = bias[c];

    float4 v = x4[idx];

    // Halo from neighbor lanes (wave = 64 lanes on CDNA).
    float left  = __shfl_up(v.w, 1);   // lane i gets lane i-1's v.w
    float right = __shfl_down(v.x, 1); // lane i gets lane i+1's v.x

    // Wave-edge lanes fetch across the wave boundary (or zero at row edges).
    // Note: i4==0 implies lane==0, i4==L4-1 implies lane==63.
    long base = (long)idx * 4;
    if (lane == 0)  left  = (i4 == 0)      ? 0.0f : x[base - 1];
    if (lane == 63) right = (i4 == L4 - 1) ? 0.0f : x[base + 4];

    float4 o;
    o.x = fmaf(w0, left, fmaf(w1, v.x, fmaf(w2, v.y, bc)));
    o.y = fmaf(w0, v.x,  fmaf(w1, v.y, fmaf(w2, v.z, bc)));
    o.z = fmaf(w0, v.y,  fmaf(w1, v.z, fmaf(w2, v.w, bc)));
    o.w = fmaf(w0, v.z,  fmaf(w1, v.w, fmaf(w2, right, bc)));

    out4[idx] = o;
}

extern "C" void kernel_launch(void* const* d_in, const int* in_sizes, int n_in,
                              void* d_out, int out_size, void* d_ws, size_t ws_size,
                              hipStream_t stream)
{
    const float* x    = (const float*)d_in[0];  // [B,C,L]
    const float* w    = (const float*)d_in[1];  // [C,3]
    const float* bias = (const float*)d_in[2];  // [C]
    float* out        = (float*)d_out;

    const int block = 256;
    const int grid  = TOTAL4 / block;           // 32768, exact

    dwconv1d_kernel<<<grid, block, 0, stream>>>(
        (const float4*)x, x, w, bias, (float4*)out);
}